// Round 2
// baseline (22831.882 us; speedup 1.0000x reference)
//
#include <hip/hip_runtime.h>
#include <math.h>

#define N_TOK   131072
#define NE      1024
#define EDIM    256
#define MARGIN  1.0e-4f // ulp(256..512)=3.05e-5 + 2*screen_err(~1.4e-5) w/ 2x safety

// Screen geometry (round-0 proven resource shape): 64x64 tile, BK=64, 4x4 micro.
#define BM      64
#define BN      64
#define BK      64
#define LDK     68      // padded LDS row stride (floats): stride 4 mod 32 banks, <=2-way
#define NPHASE  64      // (NE/BN) * (EDIM/BK) = 16 tiles * 4 k-chunks

// ---------------------------------------------------------------------------
// numpy pairwise sum replica for sum(v*v) over 256 contiguous floats.
// (verbatim from validated kernel — do not touch)
__device__ __forceinline__ float np_sumsq_256(const float* q) {
    float b[2];
#pragma unroll
    for (int blk = 0; blk < 2; ++blk) {
        const float* a = q + blk * 128;
        float r0 = __fmul_rn(a[0], a[0]), r1 = __fmul_rn(a[1], a[1]);
        float r2 = __fmul_rn(a[2], a[2]), r3 = __fmul_rn(a[3], a[3]);
        float r4 = __fmul_rn(a[4], a[4]), r5 = __fmul_rn(a[5], a[5]);
        float r6 = __fmul_rn(a[6], a[6]), r7 = __fmul_rn(a[7], a[7]);
        for (int i = 8; i < 128; i += 8) {
            r0 = __fadd_rn(r0, __fmul_rn(a[i + 0], a[i + 0]));
            r1 = __fadd_rn(r1, __fmul_rn(a[i + 1], a[i + 1]));
            r2 = __fadd_rn(r2, __fmul_rn(a[i + 2], a[i + 2]));
            r3 = __fadd_rn(r3, __fmul_rn(a[i + 3], a[i + 3]));
            r4 = __fadd_rn(r4, __fmul_rn(a[i + 4], a[i + 4]));
            r5 = __fadd_rn(r5, __fmul_rn(a[i + 5], a[i + 5]));
            r6 = __fadd_rn(r6, __fmul_rn(a[i + 6], a[i + 6]));
            r7 = __fadd_rn(r7, __fmul_rn(a[i + 7], a[i + 7]));
        }
        b[blk] = __fadd_rn(__fadd_rn(__fadd_rn(r0, r1), __fadd_rn(r2, r3)),
                           __fadd_rn(__fadd_rn(r4, r5), __fadd_rn(r6, r7)));
    }
    return __fadd_rn(b[0], b[1]);
}

// ---------------------------------------------------------------------------
// Kernel 0: sw2f[c] = np-replica fp32 of sum(w_c^2). Also zeroes rescue count.
__global__ void sw2_np_kernel(const float* __restrict__ w, float* __restrict__ sw2,
                              int* __restrict__ rcount) {
    int row = blockIdx.x * 256 + threadIdx.x;
    sw2[row] = np_sumsq_256(&w[row * EDIM]);
    if (row == 0) *rcount = 0;
}

// ---------------------------------------------------------------------------
// Kernel 1: screen. Round-0 geometry (BM=BN=BK=64, 4x4 micro, LDK=68 pad),
// single LDS buffer + register prefetch of next phase (issue-early/write-late).
// Near-ties appended to a global rescue list instead of in-block rescue.
__global__ __launch_bounds__(256, 4) void screen_kernel(
    const float* __restrict__ x, const float* __restrict__ w,
    const float* __restrict__ sw2, float* __restrict__ idxo,
    int* __restrict__ rlist, int* __restrict__ rcount)
{
    __shared__ float xs[BM * LDK];     // 17 KB
    __shared__ float wls[BN * LDK];    // 17 KB  -> 34 KB total, 4 blocks/CU

    const int t    = threadIdx.x;
    const int tx   = t & 15;
    const int ty   = t >> 4;
    const size_t row0 = (size_t)blockIdx.x * BM;

    float bestv[4], secv[4];
    int   besti[4];
#pragma unroll
    for (int i = 0; i < 4; ++i) { bestv[i] = 3.4e38f; secv[i] = 3.4e38f; besti[i] = 0; }

    // staging registers: stg[0..3] = x chunk, stg[4..7] = w chunk
    float4 stg[8];

    // prologue: load phase 0 (tile 0, kc 0)
    {
#pragma unroll
        for (int q = 0; q < 4; ++q) {
            int g = t + 256 * q;
            int r = g >> 4;
            int f = g & 15;
            stg[q]     = *(const float4*)&x[(row0 + r) * EDIM + 4 * f];
            stg[4 + q] = *(const float4*)&w[(size_t)r * EDIM + 4 * f];
        }
    }

    for (int tile = 0; tile < NE / BN; ++tile) {
        float acc[4][4];
#pragma unroll
        for (int i = 0; i < 4; ++i)
#pragma unroll
            for (int j = 0; j < 4; ++j) acc[i][j] = 0.f;

        for (int kc = 0; kc < EDIM / BK; ++kc) {
            const int p = tile * 4 + kc;

            // write-late: staged regs -> LDS
#pragma unroll
            for (int q = 0; q < 4; ++q) {
                int g = t + 256 * q;
                int r = g >> 4;
                int f = g & 15;
                *(float4*)&xs[r * LDK + 4 * f]  = stg[q];
                *(float4*)&wls[r * LDK + 4 * f] = stg[4 + q];
            }
            __syncthreads();

            // issue-early: next phase's global loads (latency hides under FMAs)
            if (p < NPHASE - 1) {
                const int np_  = p + 1;
                const int ntile = np_ >> 2;
                const int nkc   = np_ & 3;
#pragma unroll
                for (int q = 0; q < 4; ++q) {
                    int g = t + 256 * q;
                    int r = g >> 4;
                    int f = g & 15;
                    stg[q]     = *(const float4*)&x[(row0 + r) * EDIM + nkc * BK + 4 * f];
                    stg[4 + q] = *(const float4*)&w[(size_t)(ntile * BN + r) * EDIM + nkc * BK + 4 * f];
                }
            }

#pragma unroll
            for (int k4 = 0; k4 < BK / 4; ++k4) {
                float4 xv[4], wv[4];
#pragma unroll
                for (int i = 0; i < 4; ++i)
                    xv[i] = *(const float4*)&xs[(ty + 16 * i) * LDK + 4 * k4];
#pragma unroll
                for (int j = 0; j < 4; ++j)
                    wv[j] = *(const float4*)&wls[(tx + 16 * j) * LDK + 4 * k4];
#pragma unroll
                for (int i = 0; i < 4; ++i)
#pragma unroll
                    for (int j = 0; j < 4; ++j)
                        acc[i][j] += xv[i].x * wv[j].x + xv[i].y * wv[j].y
                                   + xv[i].z * wv[j].z + xv[i].w * wv[j].w;
            }
            __syncthreads();
        }

        // score this code tile (identical math/order to validated kernel)
#pragma unroll
        for (int j = 0; j < 4; ++j) {
            int c = tile * BN + tx + 16 * j;
            float s2 = sw2[c];
#pragma unroll
            for (int i = 0; i < 4; ++i) {
                float d = s2 - 2.f * acc[i][j];
                if (d < bestv[i]) { secv[i] = bestv[i]; bestv[i] = d; besti[i] = c; }
                else if (d < secv[i]) secv[i] = d;
            }
        }
    }

    // merge (best, idx, second) across 16 tx lanes (same wave)
#pragma unroll
    for (int i = 0; i < 4; ++i) {
        float v  = bestv[i], s = secv[i];
        int   bi = besti[i];
#pragma unroll
        for (int off = 8; off > 0; off >>= 1) {
            float ov = __shfl_down(v, off, 16);
            float os = __shfl_down(s, off, 16);
            int   oi = __shfl_down(bi, off, 16);
            if (ov < v || (ov == v && oi < bi)) { s = fminf(os, v); v = ov; bi = oi; }
            else                                { s = fminf(s, ov); }
        }
        if (tx == 0) {
            int r = ty + 16 * i;
            idxo[row0 + r] = (float)bi;
            if (s - v < MARGIN) {
                int pos = atomicAdd(rcount, 1);
                rlist[pos] = (int)(row0 + r);
            }
        }
    }
}

// ---------------------------------------------------------------------------
// Kernel 2: rescue. One block per flagged row (grid-stride over compact list).
// Math verbatim from the validated in-block rescue.
__global__ __launch_bounds__(256) void rescue_kernel(
    const float* __restrict__ x, const float* __restrict__ w,
    const float* __restrict__ sw2, float* __restrict__ idxo,
    const int* __restrict__ rlist, const int* __restrict__ rcount)
{
    __shared__ float xsr[EDIM];
    __shared__ float sx2sh;
    __shared__ float rrv[4];
    __shared__ int   rri[4];

    const int t = threadIdx.x;
    const int lane = t & 63, wvid = t >> 6;
    const int cnt = *rcount;

    for (int li = blockIdx.x; li < cnt; li += gridDim.x) {
        const int row = rlist[li];
        xsr[t] = x[(size_t)row * EDIM + t];
        __syncthreads();
        if (t == 0) sx2sh = np_sumsq_256(xsr);
        __syncthreads();
        const float sx2f = sx2sh;
        float bestd = 3.4e38f;
        int   bestc = 0;
#pragma unroll
        for (int jj = 0; jj < 4; ++jj) {
            int c = jj * 256 + t;
            const float4* wc = (const float4*)&w[c * EDIM];
            double acc = 0.0;
            for (int k4 = 0; k4 < 64; ++k4) {
                float4 wv = wc[k4];
                float4 xv = *(const float4*)&xsr[4 * k4];
                acc = fma((double)wv.x, (double)xv.x, acc);
                acc = fma((double)wv.y, (double)xv.y, acc);
                acc = fma((double)wv.z, (double)xv.z, acc);
                acc = fma((double)wv.w, (double)xv.w, acc);
            }
            float m  = (float)acc;                        // exact-rounded sgemm value
            float t1 = __fadd_rn(sx2f, sw2[c]);           // (sx2 + sw2) fp32
            float d  = __fsub_rn(t1, __fmul_rn(2.0f, m)); // ... - 2*m  fp32
            if (d < bestd) { bestd = d; bestc = c; }      // jj asc -> low c on ties
        }
#pragma unroll
        for (int off = 32; off > 0; off >>= 1) {
            float od = __shfl_down(bestd, off, 64);
            int   oc = __shfl_down(bestc, off, 64);
            if (od < bestd || (od == bestd && oc < bestc)) { bestd = od; bestc = oc; }
        }
        if (lane == 0) { rrv[wvid] = bestd; rri[wvid] = bestc; }
        __syncthreads();
        if (t == 0) {
            float bv = rrv[0]; int bi = rri[0];
#pragma unroll
            for (int q = 1; q < 4; ++q)
                if (rrv[q] < bv || (rrv[q] == bv && rri[q] < bi)) { bv = rrv[q]; bi = rri[q]; }
            idxo[row] = (float)bi;
        }
        __syncthreads();   // protect xsr before next list entry
    }
}

// ---------------------------------------------------------------------------
// Kernel 3: gather z_q rows from final indices. 64 rows per block.
__global__ __launch_bounds__(256) void gather_kernel(
    const float* __restrict__ w, const float* __restrict__ idxo,
    float* __restrict__ zq)
{
    const int t = threadIdx.x;
    const int g = t >> 6, f = t & 63;
    const size_t base = (size_t)blockIdx.x * 64;
#pragma unroll 4
    for (int rr = 0; rr < 16; ++rr) {
        size_t row = base + rr * 4 + g;
        int ci = (int)idxo[row];
        float4 v = *(const float4*)&w[(size_t)ci * EDIM + 4 * f];
        *(float4*)&zq[row * EDIM + 4 * f] = v;
    }
}

// ---------------------------------------------------------------------------
__global__ __launch_bounds__(256) void ce_kernel(const float* __restrict__ w,
                                                 float* __restrict__ rowres) {
    __shared__ float wj[4 * EDIM];
    __shared__ float redsum[4 * 4];
    __shared__ float diagl[4];

    const int t  = threadIdx.x;
    const int j0 = blockIdx.x * 4;
    {
        int r = t >> 6, f = t & 63;
        *(float4*)&wj[r * EDIM + 4 * f] = *(const float4*)&w[(j0 + r) * EDIM + 4 * f];
    }
    __syncthreads();

    float se[4] = {0.f, 0.f, 0.f, 0.f};
    for (int kk = 0; kk < 4; ++kk) {
        int k = kk * 256 + t;
        const float4* wk = (const float4*)&w[k * EDIM];
        float d[4] = {0.f, 0.f, 0.f, 0.f};
        for (int f = 0; f < 64; ++f) {
            float4 v = wk[f];
#pragma unroll
            for (int r = 0; r < 4; ++r) {
                float4 a = *(const float4*)&wj[r * EDIM + 4 * f];
                d[r] += a.x * v.x + a.y * v.y + a.z * v.z + a.w * v.w;
            }
        }
#pragma unroll
        for (int r = 0; r < 4; ++r) {
            float l = 3.f * d[r];
            se[r] += expf(l);
            if (k == j0 + r) diagl[r] = l;
        }
    }
    const int lane = t & 63, wv = t >> 6;
#pragma unroll
    for (int r = 0; r < 4; ++r) {
        float s = se[r];
#pragma unroll
        for (int off = 32; off > 0; off >>= 1) s += __shfl_down(s, off, 64);
        if (lane == 0) redsum[r * 4 + wv] = s;
    }
    __syncthreads();
    if (t < 4) {
        float S = redsum[t * 4 + 0] + redsum[t * 4 + 1]
                + redsum[t * 4 + 2] + redsum[t * 4 + 3];
        rowres[j0 + t] = diagl[t] - logf(S);
    }
}

// ---------------------------------------------------------------------------
__global__ void loss_final(const float* __restrict__ rowres,
                           const int* __restrict__ idxp,
                           float* __restrict__ lossp) {
    __shared__ float red[4];
    const int t = threadIdx.x;
    float s = rowres[t] + rowres[t + 256] + rowres[t + 512] + rowres[t + 768];
    const int lane = t & 63, wv = t >> 6;
#pragma unroll
    for (int off = 32; off > 0; off >>= 1) s += __shfl_down(s, off, 64);
    if (lane == 0) red[wv] = s;
    __syncthreads();
    if (t == 0) {
        float tot = red[0] + red[1] + red[2] + red[3];
        float ce = -(tot / 1024.f);
        float loss = (*idxp == 0) ? ce : 0.f;
        *lossp = loss;
    }
}

// ---------------------------------------------------------------------------
extern "C" void kernel_launch(void* const* d_in, const int* in_sizes, int n_in,
                              void* d_out, int out_size, void* d_ws, size_t ws_size,
                              hipStream_t stream) {
    (void)in_sizes; (void)n_in; (void)out_size; (void)ws_size;
    const float* x   = (const float*)d_in[0];
    const float* w   = (const float*)d_in[1];
    const int*   idx = (const int*)d_in[2];

    float* outf  = (float*)d_out;
    float* zq    = outf;                                 // 131072*256 f32
    float* idxo  = outf + (size_t)N_TOK * EDIM;          // 131072 f32
    float* lossp = idxo + N_TOK;                         // 1 f32

    float* sw2    = (float*)d_ws;
    float* rowres = sw2 + NE;

    // rescue list + counter live in the TAIL of the zq region: consumed by
    // rescue_kernel, then gather_kernel overwrites all of zq afterwards.
    int* rlist  = (int*)zq + ((size_t)N_TOK * EDIM - N_TOK - 64);
    int* rcount = rlist + N_TOK;

    sw2_np_kernel<<<NE / 256, 256, 0, stream>>>(w, sw2, rcount);
    screen_kernel<<<N_TOK / BM, 256, 0, stream>>>(x, w, sw2, idxo, rlist, rcount);
    rescue_kernel<<<1024, 256, 0, stream>>>(x, w, sw2, idxo, rlist, rcount);
    gather_kernel<<<N_TOK / 64, 256, 0, stream>>>(w, idxo, zq);
    ce_kernel<<<NE / 4, 256, 0, stream>>>(w, rowres);
    loss_final<<<1, 256, 0, stream>>>(rowres, idx, lossp);
}

// Round 3
// 2235.931 us; speedup vs baseline: 10.2114x; 10.2114x over previous
//
#include <hip/hip_runtime.h>
#include <math.h>

#define N_TOK   131072
#define NE      1024
#define EDIM    256
#define MARGIN  1.0e-4f // ulp(256..512)=3.05e-5 + 2*screen_err(~1.4e-5) w/ 2x safety

// Screen geometry: 32 x-rows per block, FULL K=256 resident in LDS (loaded once).
// Codebook streamed as 16 tiles of 64 codes, each in 4 k-chunks of 64.
#define BM      32
#define BN      64
#define BK      64
#define LDX     260     // xs row stride (floats): 1040 B, 16B-aligned, stride%32==4 -> conflict-free reads
#define LDW     68      // wls row stride (floats): 272 B, 16B-aligned

// ---------------------------------------------------------------------------
// numpy pairwise sum replica for sum(v*v) over 256 contiguous floats.
// (verbatim from validated kernel — do not touch)
__device__ __forceinline__ float np_sumsq_256(const float* q) {
    float b[2];
#pragma unroll
    for (int blk = 0; blk < 2; ++blk) {
        const float* a = q + blk * 128;
        float r0 = __fmul_rn(a[0], a[0]), r1 = __fmul_rn(a[1], a[1]);
        float r2 = __fmul_rn(a[2], a[2]), r3 = __fmul_rn(a[3], a[3]);
        float r4 = __fmul_rn(a[4], a[4]), r5 = __fmul_rn(a[5], a[5]);
        float r6 = __fmul_rn(a[6], a[6]), r7 = __fmul_rn(a[7], a[7]);
        for (int i = 8; i < 128; i += 8) {
            r0 = __fadd_rn(r0, __fmul_rn(a[i + 0], a[i + 0]));
            r1 = __fadd_rn(r1, __fmul_rn(a[i + 1], a[i + 1]));
            r2 = __fadd_rn(r2, __fmul_rn(a[i + 2], a[i + 2]));
            r3 = __fadd_rn(r3, __fmul_rn(a[i + 3], a[i + 3]));
            r4 = __fadd_rn(r4, __fmul_rn(a[i + 4], a[i + 4]));
            r5 = __fadd_rn(r5, __fmul_rn(a[i + 5], a[i + 5]));
            r6 = __fadd_rn(r6, __fmul_rn(a[i + 6], a[i + 6]));
            r7 = __fadd_rn(r7, __fmul_rn(a[i + 7], a[i + 7]));
        }
        b[blk] = __fadd_rn(__fadd_rn(__fadd_rn(r0, r1), __fadd_rn(r2, r3)),
                           __fadd_rn(__fadd_rn(r4, r5), __fadd_rn(r6, r7)));
    }
    return __fadd_rn(b[0], b[1]);
}

// ---------------------------------------------------------------------------
// Kernel 0: sw2f[c] = np-replica fp32 of sum(w_c^2). Also zeroes rescue count.
__global__ void sw2_np_kernel(const float* __restrict__ w, float* __restrict__ sw2,
                              int* __restrict__ rcount) {
    int row = blockIdx.x * 256 + threadIdx.x;
    sw2[row] = np_sumsq_256(&w[row * EDIM]);
    if (row == 0) *rcount = 0;
}

// ---------------------------------------------------------------------------
// Kernel 1: screen. x-tile (32 rows, full K) staged to LDS ONCE; w streamed
// through a single 17 KB LDS buffer with short-live-range staging (no spill).
// Micro-tile: 4 rows x 2 codes per thread (8 accs). Near-ties -> global list.
__global__ __launch_bounds__(256, 2) void screen_kernel(
    const float* __restrict__ x, const float* __restrict__ w,
    const float* __restrict__ sw2, float* __restrict__ idxo,
    int* __restrict__ rlist, int* __restrict__ rcount)
{
    __shared__ float xs[BM * LDX];     // 33.3 KB, loaded once
    __shared__ float wls[BN * LDW];    // 17.4 KB, per (tile,kc) phase

    const int t    = threadIdx.x;
    const int tx   = t & 31;           // code group: codes tx, tx+32
    const int ty   = t >> 5;           // row group:  rows ty + 8*i
    const size_t row0 = (size_t)blockIdx.x * BM;

    // ---- stage x tile once (32 rows x 256 floats = 2048 float4) ----
#pragma unroll
    for (int q = 0; q < 8; ++q) {
        int idx4 = t + 256 * q;        // 0..2047
        int r    = idx4 >> 6;          // 64 float4 per row
        int c4   = idx4 & 63;
        float4 v = *(const float4*)&x[(row0 + r) * EDIM + 4 * c4];
        *(float4*)&xs[r * LDX + 4 * c4] = v;
    }
    // (barrier below, fused with first w-stage barrier)

    float bestv[4], secv[4];
    int   besti[4];
#pragma unroll
    for (int i = 0; i < 4; ++i) { bestv[i] = 3.4e38f; secv[i] = 3.4e38f; besti[i] = 0; }

    for (int tile = 0; tile < NE / BN; ++tile) {
        float acc[4][2];
#pragma unroll
        for (int i = 0; i < 4; ++i)
#pragma unroll
            for (int j = 0; j < 2; ++j) acc[i][j] = 0.f;

        for (int kc = 0; kc < EDIM / BK; ++kc) {
            __syncthreads();           // protect wls from previous phase readers
            // stage w chunk: 64 codes x 64 floats = 1024 float4, 4 per thread.
            // direct load->store: live range of each float4 is a few instrs.
#pragma unroll
            for (int q = 0; q < 4; ++q) {
                int idx4 = t + 256 * q;     // 0..1023
                int r    = idx4 >> 4;       // 16 float4 per code row
                int f    = idx4 & 15;
                float4 v = *(const float4*)&w[(size_t)(tile * BN + r) * EDIM + kc * BK + 4 * f];
                *(float4*)&wls[r * LDW + 4 * f] = v;
            }
            __syncthreads();

#pragma unroll
            for (int k4 = 0; k4 < BK / 4; ++k4) {
                float4 xv[4], wv[2];
#pragma unroll
                for (int i = 0; i < 4; ++i)
                    xv[i] = *(const float4*)&xs[(ty + 8 * i) * LDX + kc * BK + 4 * k4];
#pragma unroll
                for (int j = 0; j < 2; ++j)
                    wv[j] = *(const float4*)&wls[(tx + 32 * j) * LDW + 4 * k4];
#pragma unroll
                for (int i = 0; i < 4; ++i)
#pragma unroll
                    for (int j = 0; j < 2; ++j)
                        acc[i][j] += xv[i].x * wv[j].x + xv[i].y * wv[j].y
                                   + xv[i].z * wv[j].z + xv[i].w * wv[j].w;
            }
        }

        // score this code tile (identical math/order to validated kernel)
#pragma unroll
        for (int j = 0; j < 2; ++j) {
            int c = tile * BN + tx + 32 * j;
            float s2 = sw2[c];
#pragma unroll
            for (int i = 0; i < 4; ++i) {
                float d = s2 - 2.f * acc[i][j];
                if (d < bestv[i]) { secv[i] = bestv[i]; bestv[i] = d; besti[i] = c; }
                else if (d < secv[i]) secv[i] = d;
            }
        }
    }

    // merge (best, idx, second) across the 32 tx lanes (lower lane = lower code
    // index base, and shfl merge prefers lower index on exact ties)
#pragma unroll
    for (int i = 0; i < 4; ++i) {
        float v  = bestv[i], s = secv[i];
        int   bi = besti[i];
#pragma unroll
        for (int off = 16; off > 0; off >>= 1) {
            float ov = __shfl_down(v, off, 32);
            float os = __shfl_down(s, off, 32);
            int   oi = __shfl_down(bi, off, 32);
            if (ov < v || (ov == v && oi < bi)) { s = fminf(os, v); v = ov; bi = oi; }
            else                                { s = fminf(s, ov); }
        }
        if (tx == 0) {
            int r = ty + 8 * i;
            idxo[row0 + r] = (float)bi;
            if (s - v < MARGIN) {
                int pos = atomicAdd(rcount, 1);
                rlist[pos] = (int)(row0 + r);
            }
        }
    }
}

// ---------------------------------------------------------------------------
// Kernel 2: rescue. One block per flagged row (grid-stride over compact list).
// Math verbatim from the validated in-block rescue.
__global__ __launch_bounds__(256) void rescue_kernel(
    const float* __restrict__ x, const float* __restrict__ w,
    const float* __restrict__ sw2, float* __restrict__ idxo,
    const int* __restrict__ rlist, const int* __restrict__ rcount)
{
    __shared__ float xsr[EDIM];
    __shared__ float sx2sh;
    __shared__ float rrv[4];
    __shared__ int   rri[4];

    const int t = threadIdx.x;
    const int lane = t & 63, wvid = t >> 6;
    const int cnt = *rcount;

    for (int li = blockIdx.x; li < cnt; li += gridDim.x) {
        const int row = rlist[li];
        xsr[t] = x[(size_t)row * EDIM + t];
        __syncthreads();
        if (t == 0) sx2sh = np_sumsq_256(xsr);
        __syncthreads();
        const float sx2f = sx2sh;
        float bestd = 3.4e38f;
        int   bestc = 0;
#pragma unroll
        for (int jj = 0; jj < 4; ++jj) {
            int c = jj * 256 + t;
            const float4* wc = (const float4*)&w[c * EDIM];
            double acc = 0.0;
            for (int k4 = 0; k4 < 64; ++k4) {
                float4 wv = wc[k4];
                float4 xv = *(const float4*)&xsr[4 * k4];
                acc = fma((double)wv.x, (double)xv.x, acc);
                acc = fma((double)wv.y, (double)xv.y, acc);
                acc = fma((double)wv.z, (double)xv.z, acc);
                acc = fma((double)wv.w, (double)xv.w, acc);
            }
            float m  = (float)acc;                        // exact-rounded sgemm value
            float t1 = __fadd_rn(sx2f, sw2[c]);           // (sx2 + sw2) fp32
            float d  = __fsub_rn(t1, __fmul_rn(2.0f, m)); // ... - 2*m  fp32
            if (d < bestd) { bestd = d; bestc = c; }      // jj asc -> low c on ties
        }
#pragma unroll
        for (int off = 32; off > 0; off >>= 1) {
            float od = __shfl_down(bestd, off, 64);
            int   oc = __shfl_down(bestc, off, 64);
            if (od < bestd || (od == bestd && oc < bestc)) { bestd = od; bestc = oc; }
        }
        if (lane == 0) { rrv[wvid] = bestd; rri[wvid] = bestc; }
        __syncthreads();
        if (t == 0) {
            float bv = rrv[0]; int bi = rri[0];
#pragma unroll
            for (int q = 1; q < 4; ++q)
                if (rrv[q] < bv || (rrv[q] == bv && rri[q] < bi)) { bv = rrv[q]; bi = rri[q]; }
            idxo[row] = (float)bi;
        }
        __syncthreads();   // protect xsr before next list entry
    }
}

// ---------------------------------------------------------------------------
// Kernel 3: gather z_q rows from final indices. 64 rows per block.
__global__ __launch_bounds__(256) void gather_kernel(
    const float* __restrict__ w, const float* __restrict__ idxo,
    float* __restrict__ zq)
{
    const int t = threadIdx.x;
    const int g = t >> 6, f = t & 63;
    const size_t base = (size_t)blockIdx.x * 64;
#pragma unroll 4
    for (int rr = 0; rr < 16; ++rr) {
        size_t row = base + rr * 4 + g;
        int ci = (int)idxo[row];
        float4 v = *(const float4*)&w[(size_t)ci * EDIM + 4 * f];
        *(float4*)&zq[row * EDIM + 4 * f] = v;
    }
}

// ---------------------------------------------------------------------------
__global__ __launch_bounds__(256) void ce_kernel(const float* __restrict__ w,
                                                 float* __restrict__ rowres) {
    __shared__ float wj[4 * EDIM];
    __shared__ float redsum[4 * 4];
    __shared__ float diagl[4];

    const int t  = threadIdx.x;
    const int j0 = blockIdx.x * 4;
    {
        int r = t >> 6, f = t & 63;
        *(float4*)&wj[r * EDIM + 4 * f] = *(const float4*)&w[(j0 + r) * EDIM + 4 * f];
    }
    __syncthreads();

    float se[4] = {0.f, 0.f, 0.f, 0.f};
    for (int kk = 0; kk < 4; ++kk) {
        int k = kk * 256 + t;
        const float4* wk = (const float4*)&w[k * EDIM];
        float d[4] = {0.f, 0.f, 0.f, 0.f};
        for (int f = 0; f < 64; ++f) {
            float4 v = wk[f];
#pragma unroll
            for (int r = 0; r < 4; ++r) {
                float4 a = *(const float4*)&wj[r * EDIM + 4 * f];
                d[r] += a.x * v.x + a.y * v.y + a.z * v.z + a.w * v.w;
            }
        }
#pragma unroll
        for (int r = 0; r < 4; ++r) {
            float l = 3.f * d[r];
            se[r] += expf(l);
            if (k == j0 + r) diagl[r] = l;
        }
    }
    const int lane = t & 63, wv = t >> 6;
#pragma unroll
    for (int r = 0; r < 4; ++r) {
        float s = se[r];
#pragma unroll
        for (int off = 32; off > 0; off >>= 1) s += __shfl_down(s, off, 64);
        if (lane == 0) redsum[r * 4 + wv] = s;
    }
    __syncthreads();
    if (t < 4) {
        float S = redsum[t * 4 + 0] + redsum[t * 4 + 1]
                + redsum[t * 4 + 2] + redsum[t * 4 + 3];
        rowres[j0 + t] = diagl[t] - logf(S);
    }
}

// ---------------------------------------------------------------------------
__global__ void loss_final(const float* __restrict__ rowres,
                           const int* __restrict__ idxp,
                           float* __restrict__ lossp) {
    __shared__ float red[4];
    const int t = threadIdx.x;
    float s = rowres[t] + rowres[t + 256] + rowres[t + 512] + rowres[t + 768];
    const int lane = t & 63, wv = t >> 6;
#pragma unroll
    for (int off = 32; off > 0; off >>= 1) s += __shfl_down(s, off, 64);
    if (lane == 0) red[wv] = s;
    __syncthreads();
    if (t == 0) {
        float tot = red[0] + red[1] + red[2] + red[3];
        float ce = -(tot / 1024.f);
        float loss = (*idxp == 0) ? ce : 0.f;
        *lossp = loss;
    }
}

// ---------------------------------------------------------------------------
extern "C" void kernel_launch(void* const* d_in, const int* in_sizes, int n_in,
                              void* d_out, int out_size, void* d_ws, size_t ws_size,
                              hipStream_t stream) {
    (void)in_sizes; (void)n_in; (void)out_size; (void)ws_size;
    const float* x   = (const float*)d_in[0];
    const float* w   = (const float*)d_in[1];
    const int*   idx = (const int*)d_in[2];

    float* outf  = (float*)d_out;
    float* zq    = outf;                                 // 131072*256 f32
    float* idxo  = outf + (size_t)N_TOK * EDIM;          // 131072 f32
    float* lossp = idxo + N_TOK;                         // 1 f32

    float* sw2    = (float*)d_ws;
    float* rowres = sw2 + NE;

    // rescue list + counter live in the TAIL of the zq region: consumed by
    // rescue_kernel, then gather_kernel overwrites all of zq afterwards.
    int* rlist  = (int*)zq + ((size_t)N_TOK * EDIM - N_TOK - 64);
    int* rcount = rlist + N_TOK;

    sw2_np_kernel<<<NE / 256, 256, 0, stream>>>(w, sw2, rcount);
    screen_kernel<<<N_TOK / BM, 256, 0, stream>>>(x, w, sw2, idxo, rlist, rcount);
    rescue_kernel<<<1024, 256, 0, stream>>>(x, w, sw2, idxo, rlist, rcount);
    gather_kernel<<<N_TOK / 64, 256, 0, stream>>>(w, idxo, zq);
    ce_kernel<<<NE / 4, 256, 0, stream>>>(w, rowres);
    loss_final<<<1, 256, 0, stream>>>(rowres, idx, lossp);
}

// Round 4
// 1746.865 us; speedup vs baseline: 13.0702x; 1.2800x over previous
//
#include <hip/hip_runtime.h>
#include <math.h>

#define N_TOK   131072
#define NE      1024
#define EDIM    256
// MARGIN > ulp(d~256..512)=3.05e-5 + 2*screen_err(bf16x2-split <=~1.6e-5) with safety.
#define MARGIN  1.5e-4f

typedef __attribute__((ext_vector_type(8))) short bf16x8;  // 8 bf16 = 4 VGPRs
typedef __attribute__((ext_vector_type(4))) float f32x4;   // MFMA C/D

// ---------------------------------------------------------------------------
// numpy pairwise sum replica for sum(v*v) over 256 contiguous floats.
// (verbatim from validated kernel — do not touch)
__device__ __forceinline__ float np_sumsq_256(const float* q) {
    float b[2];
#pragma unroll
    for (int blk = 0; blk < 2; ++blk) {
        const float* a = q + blk * 128;
        float r0 = __fmul_rn(a[0], a[0]), r1 = __fmul_rn(a[1], a[1]);
        float r2 = __fmul_rn(a[2], a[2]), r3 = __fmul_rn(a[3], a[3]);
        float r4 = __fmul_rn(a[4], a[4]), r5 = __fmul_rn(a[5], a[5]);
        float r6 = __fmul_rn(a[6], a[6]), r7 = __fmul_rn(a[7], a[7]);
        for (int i = 8; i < 128; i += 8) {
            r0 = __fadd_rn(r0, __fmul_rn(a[i + 0], a[i + 0]));
            r1 = __fadd_rn(r1, __fmul_rn(a[i + 1], a[i + 1]));
            r2 = __fadd_rn(r2, __fmul_rn(a[i + 2], a[i + 2]));
            r3 = __fadd_rn(r3, __fmul_rn(a[i + 3], a[i + 3]));
            r4 = __fadd_rn(r4, __fmul_rn(a[i + 4], a[i + 4]));
            r5 = __fadd_rn(r5, __fmul_rn(a[i + 5], a[i + 5]));
            r6 = __fadd_rn(r6, __fmul_rn(a[i + 6], a[i + 6]));
            r7 = __fadd_rn(r7, __fmul_rn(a[i + 7], a[i + 7]));
        }
        b[blk] = __fadd_rn(__fadd_rn(__fadd_rn(r0, r1), __fadd_rn(r2, r3)),
                           __fadd_rn(__fadd_rn(r4, r5), __fadd_rn(r6, r7)));
    }
    return __fadd_rn(b[0], b[1]);
}

// ---------------------------------------------------------------------------
// bf16 round-to-nearest-even helpers (sign-magnitude safe; data has no NaN/Inf)
__device__ __forceinline__ unsigned short bf16_rn(float f) {
    unsigned int u = __float_as_uint(f);
    u = (u + 0x7fffu + ((u >> 16) & 1u)) >> 16;
    return (unsigned short)u;
}
__device__ __forceinline__ float bf16_f(unsigned short h) {
    return __uint_as_float(((unsigned int)h) << 16);
}

// ---------------------------------------------------------------------------
// Kernel 0: sw2f[c] = np-replica fp32 of sum(w_c^2). Also zeroes rescue count.
__global__ void sw2_np_kernel(const float* __restrict__ w, float* __restrict__ sw2,
                              int* __restrict__ rcount) {
    int row = blockIdx.x * 256 + threadIdx.x;
    sw2[row] = np_sumsq_256(&w[row * EDIM]);
    if (row == 0) *rcount = 0;
}

// ---------------------------------------------------------------------------
// Kernel P: split fp32 array into bf16 hi/lo planes (x = hi + lo + O(2^-16 x)).
// hi = RN_bf16(x); lo = RN_bf16(x - hi)  (x - hi exact by Sterbenz).
__global__ __launch_bounds__(256) void pack_kernel(
    const float* __restrict__ src, unsigned short* __restrict__ hi,
    unsigned short* __restrict__ lo, int n4)
{
    int i = blockIdx.x * blockDim.x + threadIdx.x;
    const int stride = gridDim.x * blockDim.x;
    for (; i < n4; i += stride) {
        float4 v = ((const float4*)src)[i];
        ushort4 h, l;
        h.x = bf16_rn(v.x); l.x = bf16_rn(v.x - bf16_f(h.x));
        h.y = bf16_rn(v.y); l.y = bf16_rn(v.y - bf16_f(h.y));
        h.z = bf16_rn(v.z); l.z = bf16_rn(v.z - bf16_f(h.z));
        h.w = bf16_rn(v.w); l.w = bf16_rn(v.w - bf16_f(h.w));
        ((ushort4*)hi)[i] = h;
        ((ushort4*)lo)[i] = l;
    }
}

// ---------------------------------------------------------------------------
// Kernel 1: MFMA screen. Block = 4 waves; wave wv owns 16 token rows
// (block*64 + wv*16). A-fragments (x hi/lo) resident in registers, loaded once.
// B-fragments (w hi/lo) streamed from global (1 MB, L2-hot). 3 MFMAs per
// k-step reproduce the fp32 dot to <= ~1.6e-5. Near-ties -> rescue list.
//
// mfma_f32_16x16x32_bf16 layouts (m89-verified C/D):
//   A: lane holds A[row = lane&15][k = (lane>>4)*8 .. +8]
//   B: lane holds B[k = (lane>>4)*8 .. +8][col = lane&15]   (w stored [code][k])
//   C/D: col = lane&15, row = (lane>>4)*4 + reg
__global__ __launch_bounds__(256, 2) void screen_kernel(
    const unsigned short* __restrict__ xh, const unsigned short* __restrict__ xl,
    const unsigned short* __restrict__ wh, const unsigned short* __restrict__ wl,
    const float* __restrict__ sw2, float* __restrict__ idxo,
    int* __restrict__ rlist, int* __restrict__ rcount)
{
    const int t    = threadIdx.x;
    const int lane = t & 63;
    const int wv   = t >> 6;
    const int tx   = lane & 15;     // A-row / B-col / C-col within fragment
    const int kg   = lane >> 4;     // k-group (0..3) -> k-offset kg*8
    const size_t row0 = (size_t)blockIdx.x * 64 + (size_t)wv * 16;

    // ---- A fragments resident: 8 k-steps x {hi,lo} = 64 VGPRs ----
    bf16x8 ah[8], al[8];
    {
        const unsigned short* xhp = xh + (row0 + tx) * EDIM + kg * 8;
        const unsigned short* xlp = xl + (row0 + tx) * EDIM + kg * 8;
#pragma unroll
        for (int ks = 0; ks < 8; ++ks) {
            ah[ks] = *(const bf16x8*)(xhp + ks * 32);
            al[ks] = *(const bf16x8*)(xlp + ks * 32);
        }
    }

    float bestv[4], secv[4];
    int   besti[4];
#pragma unroll
    for (int i = 0; i < 4; ++i) { bestv[i] = 3.4e38f; secv[i] = 3.4e38f; besti[i] = 0; }

    for (int n0 = 0; n0 < NE; n0 += 16) {
        const unsigned short* whp = wh + (size_t)(n0 + tx) * EDIM + kg * 8;
        const unsigned short* wlp = wl + (size_t)(n0 + tx) * EDIM + kg * 8;

        f32x4 acc0 = {0.f, 0.f, 0.f, 0.f};   // hh
        f32x4 acc1 = {0.f, 0.f, 0.f, 0.f};   // lh
        f32x4 acc2 = {0.f, 0.f, 0.f, 0.f};   // hl
#pragma unroll
        for (int ks = 0; ks < 8; ++ks) {
            bf16x8 bh = *(const bf16x8*)(whp + ks * 32);
            bf16x8 bl = *(const bf16x8*)(wlp + ks * 32);
            acc0 = __builtin_amdgcn_mfma_f32_16x16x32_bf16(ah[ks], bh, acc0, 0, 0, 0);
            acc1 = __builtin_amdgcn_mfma_f32_16x16x32_bf16(al[ks], bh, acc1, 0, 0, 0);
            acc2 = __builtin_amdgcn_mfma_f32_16x16x32_bf16(ah[ks], bl, acc2, 0, 0, 0);
        }

        const int   c  = n0 + tx;
        const float s2 = sw2[c];
#pragma unroll
        for (int i = 0; i < 4; ++i) {
            float m = (acc0[i] + acc1[i]) + acc2[i];
            float d = s2 - 2.f * m;
            if (d < bestv[i]) { secv[i] = bestv[i]; bestv[i] = d; besti[i] = c; }
            else if (d < secv[i]) secv[i] = d;
        }
    }

    // merge (best, idx, second) across the 16 tx lanes (contiguous 16-lane group)
#pragma unroll
    for (int i = 0; i < 4; ++i) {
        float v  = bestv[i], s = secv[i];
        int   bi = besti[i];
#pragma unroll
        for (int off = 8; off > 0; off >>= 1) {
            float ov = __shfl_down(v, off, 16);
            float os = __shfl_down(s, off, 16);
            int   oi = __shfl_down(bi, off, 16);
            if (ov < v || (ov == v && oi < bi)) { s = fminf(os, v); v = ov; bi = oi; }
            else                                { s = fminf(s, ov); }
        }
        if (tx == 0) {
            int r = kg * 4 + i;                 // C/D row mapping
            idxo[row0 + r] = (float)bi;
            if (s - v < MARGIN) {
                int pos = atomicAdd(rcount, 1);
                rlist[pos] = (int)(row0 + r);
            }
        }
    }
}

// ---------------------------------------------------------------------------
// Kernel 2: rescue. One block per flagged row (grid-stride over compact list).
// Math verbatim from the validated in-block rescue (reads original fp32 x,w).
__global__ __launch_bounds__(256) void rescue_kernel(
    const float* __restrict__ x, const float* __restrict__ w,
    const float* __restrict__ sw2, float* __restrict__ idxo,
    const int* __restrict__ rlist, const int* __restrict__ rcount)
{
    __shared__ float xsr[EDIM];
    __shared__ float sx2sh;
    __shared__ float rrv[4];
    __shared__ int   rri[4];

    const int t = threadIdx.x;
    const int lane = t & 63, wvid = t >> 6;
    const int cnt = *rcount;

    for (int li = blockIdx.x; li < cnt; li += gridDim.x) {
        const int row = rlist[li];
        xsr[t] = x[(size_t)row * EDIM + t];
        __syncthreads();
        if (t == 0) sx2sh = np_sumsq_256(xsr);
        __syncthreads();
        const float sx2f = sx2sh;
        float bestd = 3.4e38f;
        int   bestc = 0;
#pragma unroll
        for (int jj = 0; jj < 4; ++jj) {
            int c = jj * 256 + t;
            const float4* wc = (const float4*)&w[c * EDIM];
            double acc = 0.0;
            for (int k4 = 0; k4 < 64; ++k4) {
                float4 wv = wc[k4];
                float4 xv = *(const float4*)&xsr[4 * k4];
                acc = fma((double)wv.x, (double)xv.x, acc);
                acc = fma((double)wv.y, (double)xv.y, acc);
                acc = fma((double)wv.z, (double)xv.z, acc);
                acc = fma((double)wv.w, (double)xv.w, acc);
            }
            float m  = (float)acc;                        // exact-rounded sgemm value
            float t1 = __fadd_rn(sx2f, sw2[c]);           // (sx2 + sw2) fp32
            float d  = __fsub_rn(t1, __fmul_rn(2.0f, m)); // ... - 2*m  fp32
            if (d < bestd) { bestd = d; bestc = c; }      // jj asc -> low c on ties
        }
#pragma unroll
        for (int off = 32; off > 0; off >>= 1) {
            float od = __shfl_down(bestd, off, 64);
            int   oc = __shfl_down(bestc, off, 64);
            if (od < bestd || (od == bestd && oc < bestc)) { bestd = od; bestc = oc; }
        }
        if (lane == 0) { rrv[wvid] = bestd; rri[wvid] = bestc; }
        __syncthreads();
        if (t == 0) {
            float bv = rrv[0]; int bi = rri[0];
#pragma unroll
            for (int q = 1; q < 4; ++q)
                if (rrv[q] < bv || (rrv[q] == bv && rri[q] < bi)) { bv = rrv[q]; bi = rri[q]; }
            idxo[row] = (float)bi;
        }
        __syncthreads();   // protect xsr before next list entry
    }
}

// ---------------------------------------------------------------------------
// Kernel 3: gather z_q rows from final indices. 64 rows per block.
// Runs AFTER rescue; overwrites the zq region (which held the bf16 planes).
__global__ __launch_bounds__(256) void gather_kernel(
    const float* __restrict__ w, const float* __restrict__ idxo,
    float* __restrict__ zq)
{
    const int t = threadIdx.x;
    const int g = t >> 6, f = t & 63;
    const size_t base = (size_t)blockIdx.x * 64;
#pragma unroll 4
    for (int rr = 0; rr < 16; ++rr) {
        size_t row = base + rr * 4 + g;
        int ci = (int)idxo[row];
        float4 v = *(const float4*)&w[(size_t)ci * EDIM + 4 * f];
        *(float4*)&zq[row * EDIM + 4 * f] = v;
    }
}

// ---------------------------------------------------------------------------
__global__ __launch_bounds__(256) void ce_kernel(const float* __restrict__ w,
                                                 float* __restrict__ rowres) {
    __shared__ float wj[4 * EDIM];
    __shared__ float redsum[4 * 4];
    __shared__ float diagl[4];

    const int t  = threadIdx.x;
    const int j0 = blockIdx.x * 4;
    {
        int r = t >> 6, f = t & 63;
        *(float4*)&wj[r * EDIM + 4 * f] = *(const float4*)&w[(j0 + r) * EDIM + 4 * f];
    }
    __syncthreads();

    float se[4] = {0.f, 0.f, 0.f, 0.f};
    for (int kk = 0; kk < 4; ++kk) {
        int k = kk * 256 + t;
        const float4* wk = (const float4*)&w[k * EDIM];
        float d[4] = {0.f, 0.f, 0.f, 0.f};
        for (int f = 0; f < 64; ++f) {
            float4 v = wk[f];
#pragma unroll
            for (int r = 0; r < 4; ++r) {
                float4 a = *(const float4*)&wj[r * EDIM + 4 * f];
                d[r] += a.x * v.x + a.y * v.y + a.z * v.z + a.w * v.w;
            }
        }
#pragma unroll
        for (int r = 0; r < 4; ++r) {
            float l = 3.f * d[r];
            se[r] += expf(l);
            if (k == j0 + r) diagl[r] = l;
        }
    }
    const int lane = t & 63, wv = t >> 6;
#pragma unroll
    for (int r = 0; r < 4; ++r) {
        float s = se[r];
#pragma unroll
        for (int off = 32; off > 0; off >>= 1) s += __shfl_down(s, off, 64);
        if (lane == 0) redsum[r * 4 + wv] = s;
    }
    __syncthreads();
    if (t < 4) {
        float S = redsum[t * 4 + 0] + redsum[t * 4 + 1]
                + redsum[t * 4 + 2] + redsum[t * 4 + 3];
        rowres[j0 + t] = diagl[t] - logf(S);
    }
}

// ---------------------------------------------------------------------------
__global__ void loss_final(const float* __restrict__ rowres,
                           const int* __restrict__ idxp,
                           float* __restrict__ lossp) {
    __shared__ float red[4];
    const int t = threadIdx.x;
    float s = rowres[t] + rowres[t + 256] + rowres[t + 512] + rowres[t + 768];
    const int lane = t & 63, wv = t >> 6;
#pragma unroll
    for (int off = 32; off > 0; off >>= 1) s += __shfl_down(s, off, 64);
    if (lane == 0) red[wv] = s;
    __syncthreads();
    if (t == 0) {
        float tot = red[0] + red[1] + red[2] + red[3];
        float ce = -(tot / 1024.f);
        float loss = (*idxp == 0) ? ce : 0.f;
        *lossp = loss;
    }
}

// ---------------------------------------------------------------------------
extern "C" void kernel_launch(void* const* d_in, const int* in_sizes, int n_in,
                              void* d_out, int out_size, void* d_ws, size_t ws_size,
                              hipStream_t stream) {
    (void)in_sizes; (void)n_in; (void)out_size; (void)ws_size;
    const float* x   = (const float*)d_in[0];
    const float* w   = (const float*)d_in[1];
    const int*   idx = (const int*)d_in[2];

    float* outf  = (float*)d_out;
    float* zq    = outf;                                 // 131072*256 f32
    float* idxo  = outf + (size_t)N_TOK * EDIM;          // 131072 f32
    float* lossp = idxo + N_TOK;                         // 1 f32

    // x bf16 planes exactly fill the zq region (2 * N_TOK*256 * 2B = zq bytes).
    // They are dead before gather_kernel rewrites zq.
    unsigned short* xh = (unsigned short*)zq;
    unsigned short* xl = xh + (size_t)N_TOK * EDIM;

    // workspace: sw2(4KB) | rowres(4KB) | wh(512KB) | wl(512KB) | rcount | rlist(512KB)
    float* sw2    = (float*)d_ws;
    float* rowres = sw2 + NE;
    unsigned short* wh = (unsigned short*)(rowres + NE);
    unsigned short* wl = wh + (size_t)NE * EDIM;
    int* rcount = (int*)(wl + (size_t)NE * EDIM);
    int* rlist  = rcount + 64;

    pack_kernel<<<2048, 256, 0, stream>>>(x, xh, xl, N_TOK * EDIM / 4);
    pack_kernel<<<256, 256, 0, stream>>>(w, wh, wl, NE * EDIM / 4);
    sw2_np_kernel<<<NE / 256, 256, 0, stream>>>(w, sw2, rcount);
    screen_kernel<<<N_TOK / 64, 256, 0, stream>>>(xh, xl, wh, wl, sw2, idxo,
                                                  rlist, rcount);
    rescue_kernel<<<1024, 256, 0, stream>>>(x, w, sw2, idxo, rlist, rcount);
    gather_kernel<<<N_TOK / 64, 256, 0, stream>>>(w, idxo, zq);
    ce_kernel<<<NE / 4, 256, 0, stream>>>(w, rowres);
    loss_final<<<1, 256, 0, stream>>>(rowres, idx, lossp);
}